// Round 10
// baseline (671.139 us; speedup 1.0000x reference)
//
#include <hip/hip_runtime.h>
#include <hip/hip_bf16.h>
#include <math.h>
#include <stdint.h>

// ---------------------------------------------------------------------------
// Full U-Mamba block. R10: scan_k redesigned as one-sequence-per-wave,
// barrier-free body: lane owns 2 channels (32 indep exp chains), post-LN via
// in-wave shfl butterfly inside the l-loop (no s_yb, no stats pass, no final
// pass), strength-reduced pointer arithmetic. Everything else = R9.
// ---------------------------------------------------------------------------

typedef __attribute__((ext_vector_type(8))) short short8;   // 8 bf16 = 4 VGPR
typedef __attribute__((ext_vector_type(4))) float f32x4;

__device__ __forceinline__ float siluf(float x){ return x * (1.0f / (1.0f + __expf(-x))); }
__device__ __forceinline__ float softplusf(float x){ return fmaxf(x, 0.0f) + log1pf(__expf(-fabsf(x))); }
__device__ __forceinline__ float b2f(short s){
  unsigned int u = ((unsigned int)(unsigned short)s) << 16;
  float f; __builtin_memcpy(&f, &u, 4); return f;
}
__device__ __forceinline__ short f2b(float v){
  __hip_bfloat16 h = __float2bfloat16(v);
  unsigned short u; __builtin_memcpy(&u, &h, 2); return (short)u;
}

// async global->LDS, 16B per lane; LDS dest is wave-uniform base + lane*16.
__device__ __forceinline__ void gld_lds16(const void* g, void* l){
  __builtin_amdgcn_global_load_lds(
      (__attribute__((address_space(1))) void*)(uintptr_t)g,
      (__attribute__((address_space(3))) void*)(uint32_t)(uintptr_t)l,
      16, 0, 0);
}

// ---------------------------------------------------------------------------
// One-shot setup: zero xpad | pack conv weights a/b -> bf16 [tap][co][ci] |
// mamba weight bf16 tables | negA2[s] = -softplus(A_log[s]) * log2(e).
// ---------------------------------------------------------------------------
__global__ __launch_bounds__(256) void setup_k(uint4* __restrict__ xz,
    const float* __restrict__ cr1w, const float* __restrict__ cr2w,
    const float* __restrict__ lw, const float* __restrict__ rwt,
    const float* __restrict__ dwt, const float* __restrict__ bw,
    const float* __restrict__ cwp, const float* __restrict__ owt,
    const float* __restrict__ alog,
    __hip_bfloat16* __restrict__ W4a, __hip_bfloat16* __restrict__ W4b,
    __hip_bfloat16* __restrict__ Wlr, __hip_bfloat16* __restrict__ Wd,
    __hip_bfloat16* __restrict__ oWp, float* __restrict__ negA2)
{
  int i = blockIdx.x * 256 + threadIdx.x;
  if (i < 628864){ uint4 z; z.x = z.y = z.z = z.w = 0u; xz[i] = z; return; }
  i -= 628864;
  if (i < 110592){
    int tap = i >> 12, co = (i >> 6) & 63, ci = i & 63;
    W4a[i] = __float2bfloat16(cr1w[(co * 64 + ci) * 27 + tap]); return;
  }
  i -= 110592;
  if (i < 110592){
    int tap = i >> 12, co = (i >> 6) & 63, ci = i & 63;
    W4b[i] = __float2bfloat16(cr2w[(co * 64 + ci) * 27 + tap]); return;
  }
  i -= 110592;
  if (i < 16384){
    int row = i >> 6, c = i & 63;
    float v = (row < 128) ? lw[row * 64 + c] : rwt[(row - 128) * 64 + c];
    Wlr[i] = __float2bfloat16(v); return;
  }
  i -= 16384;
  if (i < 20480){
    int row = i >> 7, k = i & 127;
    float v = (row < 128) ? dwt[row * 128 + k]
            : (row < 144 ? bw[(row - 128) * 128 + k] : cwp[(row - 144) * 128 + k]);
    Wd[i] = __float2bfloat16(v); return;
  }
  i -= 20480;
  if (i < 8192){ oWp[i] = __float2bfloat16(owt[i]); return; }
  i -= 8192;
  if (i < 16){ negA2[i] = -softplusf(alog[i]) * 1.44269504088896f; return; }
}

// ---------------------------------------------------------------------------
// Pack fp32 NCDHW -> padded channels-last bf16 [b][h+1][w+1][d+1][c] (conv1).
// ---------------------------------------------------------------------------
__global__ __launch_bounds__(256) void pack_k(const float* __restrict__ xin,
                                              __hip_bfloat16* __restrict__ xpad)
{
  __shared__ float lds[64 * 33];
  const int t = threadIdx.x, blk = blockIdx.x;
  const int b = blk >> 10, h = (blk >> 5) & 31, w = blk & 31;
  const size_t rbase = ((size_t)(b * 64) << 15) + h * 1024 + w * 32;
  #pragma unroll
  for (int r = 0; r < 8; r++){
    int c = r * 8 + (t >> 5), d = t & 31;
    lds[c * 33 + d] = xin[rbase + (size_t)c * 32768 + d];
  }
  __syncthreads();
  const size_t wbase = (size_t)b * 2515456 + (size_t)(h + 1) * 73984 + (w + 1) * 2176 + 64;
  #pragma unroll
  for (int r = 0; r < 8; r++){
    int d = r * 4 + (t >> 6), c = t & 63;
    xpad[wbase + d * 64 + c] = __float2bfloat16(lds[c * 33 + d]);
  }
}

// ---------------------------------------------------------------------------
// Conv3d implicit GEMM, bf16 MFMA 16x16x32, LDS-staged (m97 pattern, R8).
// ---------------------------------------------------------------------------
__global__ __launch_bounds__(256) void conv_mfma_k(const __hip_bfloat16* __restrict__ xpad,
    const __hip_bfloat16* __restrict__ W4, float* __restrict__ y)
{
  __shared__ short smem[6144];   // [0,4096): B tile; [4096,6144): A tile

  const int t = threadIdx.x;
  const int wave = t >> 6, lane = t & 63;
  const int quad = lane >> 4, ln = lane & 15;

  const int blk = blockIdx.x;          // 512 blocks
  const int xcd = blk & 7, j = blk >> 3;
  const int b = j >> 5, jj = j & 31;
  const int h = xcd * 4 + (jj >> 3);
  const int w0 = (jj & 7) * 4;

  const int bcol = (lane >> 2) * 64 + (lane & 3) * 8;
  const __hip_bfloat16* Bg = xpad + (size_t)b * 2515456 + (size_t)h * 73984
                                  + (size_t)(w0 + wave) * 2176 + bcol;
  const __hip_bfloat16* Ag = W4 + wave * 1024 + bcol;
  short* Bl0 = &smem[wave * 1024];
  short* Bl1 = &smem[wave * 1024 + 512];
  short* Al  = &smem[4096 + wave * 512];

  f32x4 acc[2][4];
  #pragma unroll
  for (int jn = 0; jn < 2; jn++)
    #pragma unroll
    for (int m = 0; m < 4; m++) acc[jn][m] = (f32x4){0.f, 0.f, 0.f, 0.f};

  const int aoff = ln * 32 + quad * 8;
  const int boff = (wave * 32 + ln) * 32 + quad * 8;

  for (int s = 0; s < 54; s++){
    const int t1 = s >> 1, ch = s & 1;
    const int ki = t1 / 9, kj = (t1 / 3) % 3, kk = t1 % 3;
    const int tapoff = ki * 73984 + kj * 2176 + kk * 64 + ch * 32;

    __syncthreads();
    gld_lds16(Bg + tapoff,        Bl0);
    gld_lds16(Bg + tapoff + 1024, Bl1);
    gld_lds16(Ag + t1 * 4096 + ch * 32, Al);
    __syncthreads();

    short8 a0 = *(const short8*)&smem[4096 + aoff];
    short8 a1 = *(const short8*)&smem[4096 + 512 + aoff];
    short8 a2 = *(const short8*)&smem[4096 + 1024 + aoff];
    short8 a3 = *(const short8*)&smem[4096 + 1536 + aoff];
    short8 b0 = *(const short8*)&smem[boff];
    short8 b1 = *(const short8*)&smem[boff + 512];

    acc[0][0] = __builtin_amdgcn_mfma_f32_16x16x32_bf16(a0, b0, acc[0][0], 0, 0, 0);
    acc[0][1] = __builtin_amdgcn_mfma_f32_16x16x32_bf16(a1, b0, acc[0][1], 0, 0, 0);
    acc[0][2] = __builtin_amdgcn_mfma_f32_16x16x32_bf16(a2, b0, acc[0][2], 0, 0, 0);
    acc[0][3] = __builtin_amdgcn_mfma_f32_16x16x32_bf16(a3, b0, acc[0][3], 0, 0, 0);
    acc[1][0] = __builtin_amdgcn_mfma_f32_16x16x32_bf16(a0, b1, acc[1][0], 0, 0, 0);
    acc[1][1] = __builtin_amdgcn_mfma_f32_16x16x32_bf16(a1, b1, acc[1][1], 0, 0, 0);
    acc[1][2] = __builtin_amdgcn_mfma_f32_16x16x32_bf16(a2, b1, acc[1][2], 0, 0, 0);
    acc[1][3] = __builtin_amdgcn_mfma_f32_16x16x32_bf16(a3, b1, acc[1][3], 0, 0, 0);
  }

  const size_t sbase = (size_t)h * 1024 + (w0 + wave) * 32 + ln;
  #pragma unroll
  for (int jn = 0; jn < 2; jn++){
    #pragma unroll
    for (int mt = 0; mt < 4; mt++){
      #pragma unroll
      for (int reg = 0; reg < 4; reg++){
        int co = mt * 16 + quad * 4 + reg;
        y[(((size_t)(b * 64 + co)) << 15) + sbase + jn * 16] = acc[jn][mt][reg];
      }
    }
  }
}

// ---------------------------------------------------------------------------
// InstanceNorm3d stats: one block per (b,c); stats[g]=mu, stats[128+g]=rsigma.
// ---------------------------------------------------------------------------
__global__ __launch_bounds__(256) void inorm_stats_k(const float* __restrict__ y,
                                                     float* __restrict__ stats)
{
  __shared__ float ss[256], ss2[256];
  const int t = threadIdx.x, g = blockIdx.x;
  const float* p = y + (size_t)g * 32768;
  float s = 0.0f, s2 = 0.0f;
  for (int i = t; i < 32768; i += 256){ float v = p[i]; s += v; s2 += v * v; }
  ss[t] = s; ss2[t] = s2;
  __syncthreads();
  for (int off = 128; off > 0; off >>= 1){
    if (t < off){ ss[t] += ss[t + off]; ss2[t] += ss2[t + off]; }
    __syncthreads();
  }
  if (t == 0){
    float mu = ss[0] * (1.0f / 32768.0f);
    float var = ss2[0] * (1.0f / 32768.0f) - mu * mu;
    stats[g] = mu;
    stats[128 + g] = rsqrtf(var + 1e-5f);
  }
}

// ---------------------------------------------------------------------------
// Fused: InstanceNorm-apply + LeakyReLU + residual -> x1 (fp32 NCDHW)
// AND bf16 channels-last re-pack into xpad (input of conv2).
// ---------------------------------------------------------------------------
__global__ __launch_bounds__(256) void apply_pack_k(const float* __restrict__ xin,
    const float* __restrict__ y, const float* __restrict__ stats,
    float* __restrict__ x1, __hip_bfloat16* __restrict__ xpad)
{
  __shared__ float lds[64 * 33];
  const int t = threadIdx.x, blk = blockIdx.x;
  const int b = blk >> 10, h = (blk >> 5) & 31, w = blk & 31;
  const size_t rbase = ((size_t)(b * 64) << 15) + h * 1024 + w * 32;
  #pragma unroll
  for (int r = 0; r < 8; r++){
    int c = r * 8 + (t >> 5), d = t & 31;
    float mu = stats[b * 64 + c], rs = stats[128 + b * 64 + c];
    float v = (y[rbase + (size_t)c * 32768 + d] - mu) * rs;
    v = (v >= 0.0f) ? v : 0.01f * v;
    v += xin[rbase + (size_t)c * 32768 + d];
    x1[rbase + (size_t)c * 32768 + d] = v;
    lds[c * 33 + d] = v;
  }
  __syncthreads();
  const size_t wbase = (size_t)b * 2515456 + (size_t)(h + 1) * 73984 + (w + 1) * 2176 + 64;
  #pragma unroll
  for (int r = 0; r < 8; r++){
    int d = r * 4 + (t >> 6), c = t & 63;
    xpad[wbase + d * 64 + c] = __float2bfloat16(lds[c * 33 + d]);
  }
}

// ---------------------------------------------------------------------------
// Fused: InstanceNorm-apply + LeakyReLU + residual + LayerNorm over C
// -> bf16 channels-last lnx [pos][64]. x2 never materialized.
// ---------------------------------------------------------------------------
__global__ __launch_bounds__(256) void apply_ln_k(const float* __restrict__ x1,
    const float* __restrict__ y, const float* __restrict__ stats,
    const float* __restrict__ lnw, const float* __restrict__ lnb,
    __hip_bfloat16* __restrict__ lnx)
{
  __shared__ float lds[64 * 33];
  __shared__ float s_mu[32], s_rs[32];
  const int t = threadIdx.x, blk = blockIdx.x;
  const int b = blk >> 10, h = (blk >> 5) & 31, w = blk & 31;
  const size_t rbase = ((size_t)(b * 64) << 15) + h * 1024 + w * 32;
  #pragma unroll
  for (int r = 0; r < 8; r++){
    int c = r * 8 + (t >> 5), d = t & 31;
    float mu = stats[b * 64 + c], rs = stats[128 + b * 64 + c];
    float v = (y[rbase + (size_t)c * 32768 + d] - mu) * rs;
    v = (v >= 0.0f) ? v : 0.01f * v;
    lds[c * 33 + d] = v + x1[rbase + (size_t)c * 32768 + d];
  }
  __syncthreads();
  if (t < 32){
    float s = 0.f, s2 = 0.f;
    for (int c = 0; c < 64; c++){ float v = lds[c * 33 + t]; s += v; s2 += v * v; }
    float mu = s * (1.f / 64.f);
    float var = s2 * (1.f / 64.f) - mu * mu;
    s_mu[t] = mu; s_rs[t] = rsqrtf(var + 1e-5f);
  }
  __syncthreads();
  const int d = t >> 3, c0 = (t & 7) * 8;
  const int pos = b * 32768 + h * 1024 + w * 32 + d;
  const float mu = s_mu[d], rs = s_rs[d];
  short8 o;
  #pragma unroll
  for (int j = 0; j < 8; j++){
    int c = c0 + j;
    o[j] = f2b((lds[c * 33 + d] - mu) * rs * lnw[c] + lnb[c]);
  }
  *(short8*)&lnx[(size_t)pos * 64 + c0] = o;
}

// ---------------------------------------------------------------------------
// GEMM [65536,64] x [64,256] -> Lbuf (cols 0-127 raw) + Gbuf (silu, 128-255).
// ---------------------------------------------------------------------------
__global__ __launch_bounds__(256) void gemm_lr_k(const __hip_bfloat16* __restrict__ lnx,
    const __hip_bfloat16* __restrict__ Wlr, __hip_bfloat16* __restrict__ Lb,
    __hip_bfloat16* __restrict__ Gb)
{
  const int t = threadIdx.x, wave = t >> 6, lane = t & 63, quad = lane >> 4, ln = lane & 15;
  const int pos0 = blockIdx.x * 64 + wave * 16;
  f32x4 acc[16];
  #pragma unroll
  for (int nt = 0; nt < 16; nt++) acc[nt] = (f32x4){0.f, 0.f, 0.f, 0.f};
  #pragma unroll
  for (int ks = 0; ks < 2; ks++){
    short8 a = *(const short8*)&lnx[(size_t)(pos0 + ln) * 64 + ks * 32 + quad * 8];
    #pragma unroll
    for (int nt = 0; nt < 16; nt++){
      short8 bv = *(const short8*)&Wlr[(nt * 16 + ln) * 64 + ks * 32 + quad * 8];
      acc[nt] = __builtin_amdgcn_mfma_f32_16x16x32_bf16(a, bv, acc[nt], 0, 0, 0);
    }
  }
  #pragma unroll
  for (int nt = 0; nt < 16; nt++){
    int col = nt * 16 + ln;
    #pragma unroll
    for (int reg = 0; reg < 4; reg++){
      int pos = pos0 + quad * 4 + reg;
      float v = acc[nt][reg];
      if (col < 128) Lb[(size_t)pos * 128 + col] = __float2bfloat16(v);
      else           Gb[(size_t)pos * 128 + col - 128] = __float2bfloat16(siluf(v));
    }
  }
}

// ---------------------------------------------------------------------------
// FUSED per-axis: conv1d(k=4)+silu -> LDS tile -> GEMM [64,128]x[128,160].
// ---------------------------------------------------------------------------
__global__ __launch_bounds__(256) void dbc_k(const __hip_bfloat16* __restrict__ Lb,
    const float* __restrict__ cw, const float* __restrict__ cb,
    const __hip_bfloat16* __restrict__ Wd, const float* __restrict__ db,
    __hip_bfloat16* __restrict__ xl, __hip_bfloat16* __restrict__ dbc, int sh)
{
  __shared__ short s_xl[64 * 136];
  const int t = threadIdx.x;
  const int pos0 = blockIdx.x * 64;
  const int sigma = 1 << sh;

  const int c0 = (t & 15) * 8;
  const int pibase = t >> 4;
  float4 w4[8]; float cbv[8];
  #pragma unroll
  for (int c = 0; c < 8; c++){ w4[c] = *(const float4*)&cw[(c0 + c) * 4]; cbv[c] = cb[c0 + c]; }

  #pragma unroll
  for (int r = 0; r < 4; r++){
    int pi = pibase + r * 16;
    int pos = pos0 + pi;
    int l = (pos >> sh) & 31;
    float acc[8];
    #pragma unroll
    for (int c = 0; c < 8; c++) acc[c] = cbv[c];
    #pragma unroll
    for (int j = 0; j < 4; j++){
      int off = 3 - j;
      if (l >= off){
        short8 lv = *(const short8*)&Lb[(size_t)(pos - off * sigma) * 128 + c0];
        #pragma unroll
        for (int c = 0; c < 8; c++){
          float wv = (j == 0) ? w4[c].x : (j == 1) ? w4[c].y : (j == 2) ? w4[c].z : w4[c].w;
          acc[c] += wv * b2f(lv[c]);
        }
      }
    }
    short8 o;
    #pragma unroll
    for (int c = 0; c < 8; c++) o[c] = f2b(siluf(acc[c]));
    *(short8*)&s_xl[pi * 136 + c0] = o;
    *(short8*)&xl[(size_t)pos * 128 + c0] = o;
  }
  __syncthreads();

  const int wave = t >> 6, lane = t & 63, quad = lane >> 4, ln = lane & 15;
  const int rowb = (wave * 16 + ln) * 136;
  f32x4 acc2[10];
  #pragma unroll
  for (int nt = 0; nt < 10; nt++) acc2[nt] = (f32x4){0.f, 0.f, 0.f, 0.f};
  #pragma unroll
  for (int ks = 0; ks < 4; ks++){
    short8 a = *(const short8*)&s_xl[rowb + ks * 32 + quad * 8];
    #pragma unroll
    for (int nt = 0; nt < 10; nt++){
      short8 bv = *(const short8*)&Wd[(nt * 16 + ln) * 128 + ks * 32 + quad * 8];
      acc2[nt] = __builtin_amdgcn_mfma_f32_16x16x32_bf16(a, bv, acc2[nt], 0, 0, 0);
    }
  }
  const int posw = pos0 + wave * 16 + quad * 4;
  #pragma unroll
  for (int nt = 0; nt < 10; nt++){
    int col = nt * 16 + ln;
    bool isd = col < 128;
    float dbv = isd ? db[col] : 0.f;
    #pragma unroll
    for (int reg = 0; reg < 4; reg++){
      float v = acc2[nt][reg];
      if (isd) v = fminf(fmaxf(softplusf(v + dbv), 1e-4f), 10.f);
      dbc[(size_t)(posw + reg) * 160 + col] = __float2bfloat16(v);
    }
  }
}

// ---------------------------------------------------------------------------
// Per-axis selective scan + gate + post-LN -> Ybuf. R10: ONE SEQUENCE PER
// WAVE (4 seqs / 256-thr block, grid 512). Lane owns channels d0=2*lane,
// d0+1: h0[16]+h1[16] in regs (32 indep exp chains). Post-LN stats via
// in-wave shfl butterfly each l; normalize+store in-loop. One barrier
// (B/C staging). Pointers strength-reduced to increments.
// ---------------------------------------------------------------------------
__global__ __launch_bounds__(256) void scan_k(const __hip_bfloat16* __restrict__ dbc,
    const __hip_bfloat16* __restrict__ xl, const __hip_bfloat16* __restrict__ Gb,
    const float* __restrict__ negA2, const float* __restrict__ pnw,
    const float* __restrict__ pnb, __hip_bfloat16* __restrict__ Yb, int axis)
{
  __shared__ float s_BC[4][1024];   // per wave: [0..511]=B, [512..1023]=C
  const int t = threadIdx.x;
  const int wv = t >> 6, lane = t & 63;
  const int seq = blockIdx.x * 4 + wv;
  const int b = seq >> 10, r1 = (seq >> 5) & 31, r0 = seq & 31;
  int base, sigma;
  if (axis == 0){      base = b * 32768 + r1 * 32 + r0;        sigma = 1024; }
  else if (axis == 1){ base = b * 32768 + r1 * 1024 + r0;      sigma = 32; }
  else {               base = b * 32768 + r1 * 1024 + r0 * 32; sigma = 1; }

  // stage B/C: 128 chunks of 16B (32 rows x 4 chunks); lane does 2 chunks
  float* sB = s_BC[wv];
  float* sC = s_BC[wv] + 512;
  #pragma unroll
  for (int i = 0; i < 2; i++){
    int c = lane * 2 + i;
    int row = c >> 2, sub = c & 3;
    short8 v = *(const short8*)&dbc[(size_t)(base + row * sigma) * 160 + 128 + sub * 8];
    float* dst = (sub < 2) ? &sB[row * 16 + sub * 8] : &sC[row * 16 + (sub - 2) * 8];
    #pragma unroll
    for (int j = 0; j < 8; j++) dst[j] = b2f(v[j]);
  }
  float A2[16], h0[16], h1[16];
  #pragma unroll
  for (int s = 0; s < 16; s++){ A2[s] = negA2[s]; h0[s] = 0.f; h1[s] = 0.f; }
  __syncthreads();

  const int d0 = lane * 2;
  const float pw0 = pnw[d0], pb0 = pnb[d0];
  const float pw1 = pnw[d0 + 1], pb1 = pnb[d0 + 1];
  const __hip_bfloat16* pd = dbc + (size_t)base * 160 + d0;
  const __hip_bfloat16* px = xl  + (size_t)base * 128 + d0;
  const __hip_bfloat16* pg = Gb  + (size_t)base * 128 + d0;
  __hip_bfloat16*       py = Yb  + (size_t)base * 128 + d0;
  const size_t sd = (size_t)sigma * 160;
  const size_t sx = (size_t)sigma * 128;

  for (int l = 0; l < 32; l++){
    unsigned int du, xu, gu;
    __builtin_memcpy(&du, pd, 4);
    __builtin_memcpy(&xu, px, 4);
    __builtin_memcpy(&gu, pg, 4);
    float dt0 = b2f((short)(du & 0xffff)), dt1 = b2f((short)(du >> 16));
    float xt0 = b2f((short)(xu & 0xffff)), xt1 = b2f((short)(xu >> 16));
    float g0  = b2f((short)(gu & 0xffff)), g1  = b2f((short)(gu >> 16));
    float dx0 = dt0 * xt0, dx1 = dt1 * xt1;
    float y0 = 0.f, y1 = 0.f;
    const float* Bl = &sB[l * 16];
    const float* Cl = &sC[l * 16];
    #pragma unroll
    for (int s = 0; s < 16; s++){
      float Bv = Bl[s], Cv = Cl[s];
      h0[s] = exp2f(dt0 * A2[s]) * h0[s] + dx0 * Bv;
      h1[s] = exp2f(dt1 * A2[s]) * h1[s] + dx1 * Bv;
      y0 += h0[s] * Cv;
      y1 += h1[s] * Cv;
    }
    y0 *= g0; y1 *= g1;
    // post-LN over d_inner=128 (64 lanes x 2): in-wave butterfly
    float s1 = y0 + y1, s2 = y0 * y0 + y1 * y1;
    #pragma unroll
    for (int m = 1; m < 64; m <<= 1){
      s1 += __shfl_xor(s1, m);
      s2 += __shfl_xor(s2, m);
    }
    float mu = s1 * (1.f / 128.f);
    float var = s2 * (1.f / 128.f) - mu * mu;
    float rs = rsqrtf(fmaxf(var, 0.f) + 1e-5f);
    unsigned short o0 = (unsigned short)f2b((y0 - mu) * rs * pw0 + pb0);
    unsigned short o1 = (unsigned short)f2b((y1 - mu) * rs * pw1 + pb1);
    unsigned int ov = (unsigned int)o0 | ((unsigned int)o1 << 16);
    __builtin_memcpy(py, &ov, 4);
    pd += sd; px += sx; pg += sx; py += sx;
  }
}

// ---------------------------------------------------------------------------
// GEMM out + weighted accumulate into d_out (pos-ordered -> coalesced).
// mode: 0=first (store), 1=middle (add), 2=last (add + residual finalize).
// ---------------------------------------------------------------------------
__global__ __launch_bounds__(256) void gemm_out_k(const __hip_bfloat16* __restrict__ Yb,
    const __hip_bfloat16* __restrict__ oW, const float* __restrict__ axw,
    const float* __restrict__ xres, const float* __restrict__ rsc,
    float* __restrict__ outp, int axis, int mode)
{
  const int t = threadIdx.x, wave = t >> 6, lane = t & 63, quad = lane >> 4, ln = lane & 15;
  const int pos0 = blockIdx.x * 64 + wave * 16;
  f32x4 acc[4];
  #pragma unroll
  for (int mt = 0; mt < 4; mt++) acc[mt] = (f32x4){0.f, 0.f, 0.f, 0.f};
  #pragma unroll
  for (int ks = 0; ks < 4; ks++){
    short8 bv = *(const short8*)&Yb[(size_t)(pos0 + ln) * 128 + ks * 32 + quad * 8];
    #pragma unroll
    for (int mt = 0; mt < 4; mt++){
      short8 a = *(const short8*)&oW[(mt * 16 + ln) * 128 + ks * 32 + quad * 8];
      acc[mt] = __builtin_amdgcn_mfma_f32_16x16x32_bf16(a, bv, acc[mt], 0, 0, 0);
    }
  }
  float a0 = axw[0], a1 = axw[1], a2 = axw[2];
  float mx = fmaxf(a0, fmaxf(a1, a2));
  float e0 = __expf(a0 - mx), e1 = __expf(a1 - mx), e2 = __expf(a2 - mx);
  float wax = ((axis == 0) ? e0 : (axis == 1) ? e1 : e2) / (e0 + e1 + e2);
  float rs = rsc[0];
  const int pos = pos0 + ln;
  const int bb = pos >> 15, hwd = pos & 32767;
  #pragma unroll
  for (int mt = 0; mt < 4; mt++){
    #pragma unroll
    for (int reg = 0; reg < 4; reg++){
      int co = mt * 16 + quad * 4 + reg;
      size_t idx = (((size_t)(bb * 64 + co)) << 15) + hwd;
      float v = acc[mt][reg] * wax;
      if (mode == 0)      outp[idx] = v;
      else if (mode == 1) outp[idx] += v;
      else                outp[idx] = xres[idx] + rs * (outp[idx] + v);
    }
  }
}

// ---------------------------------------------------------------------------
extern "C" void kernel_launch(void* const* d_in, const int* in_sizes, int n_in,
                              void* d_out, int out_size, void* d_ws, size_t ws_size,
                              hipStream_t stream)
{
  const float* x      = (const float*)d_in[0];
  const float* cr1w   = (const float*)d_in[1];
  const float* cr2w   = (const float*)d_in[3];
  const float* ln_w   = (const float*)d_in[5];
  const float* ln_b   = (const float*)d_in[6];
  const float* left_w = (const float*)d_in[7];
  const float* c1dw   = (const float*)d_in[8];
  const float* c1db   = (const float*)d_in[9];
  const float* dw     = (const float*)d_in[10];
  const float* db     = (const float*)d_in[11];
  const float* bpw    = (const float*)d_in[12];
  const float* cpw    = (const float*)d_in[13];
  const float* alog   = (const float*)d_in[14];
  const float* rw     = (const float*)d_in[15];
  const float* pnw    = (const float*)d_in[16];
  const float* pnb    = (const float*)d_in[17];
  const float* ow     = (const float*)d_in[18];
  const float* rsc    = (const float*)d_in[19];
  const float* axw    = (const float*)d_in[20];
  float* out = (float*)d_out;                       // conv raw out, then mamba accum
  float* wsf = (float*)d_ws;

  float* buf1   = wsf;                                         // x1 fp32; later xl bf16 alias
  float* stats  = wsf + 4194304;                               // 256 f
  float* negA2  = wsf + 4194560;                               // 16 f
  __hip_bfloat16* W4a  = (__hip_bfloat16*)(wsf + 4194816);     // 110,592 bf16
  __hip_bfloat16* W4b  = W4a + 110592;
  __hip_bfloat16* Wlr  = (__hip_bfloat16*)(wsf + 4305408);     // 16,384 bf16
  __hip_bfloat16* Wdbc = (__hip_bfloat16*)(wsf + 4313600);     // 20,480 bf16
  __hip_bfloat16* oWp  = (__hip_bfloat16*)(wsf + 4323840);     // 8,192 bf16
  __hip_bfloat16* xpad = (__hip_bfloat16*)(wsf + 4327936);     // 5,030,912 bf16
  __hip_bfloat16* lnx  = xpad;                                 // alias (post-conv)
  __hip_bfloat16* Lbuf = (__hip_bfloat16*)(wsf + 6843392);     // 8,388,608 bf16
  __hip_bfloat16* Gbuf = (__hip_bfloat16*)(wsf + 11037696);    // 8,388,608 bf16
  __hip_bfloat16* dbc  = (__hip_bfloat16*)(wsf + 15232000);    // 10,485,760 bf16
  __hip_bfloat16* Ybuf = (__hip_bfloat16*)(wsf + 20474880);    // 8,388,608 bf16
  __hip_bfloat16* xl   = (__hip_bfloat16*)buf1;                // alias (x1 dead after apply_ln)

  setup_k<<<3497, 256, 0, stream>>>((uint4*)xpad, cr1w, cr2w, left_w, rw, dw, bpw, cpw, ow,
                                    alog, W4a, W4b, Wlr, Wdbc, oWp, negA2);

  // conv-res block 1
  pack_k<<<2048, 256, 0, stream>>>(x, xpad);
  conv_mfma_k<<<512, 256, 0, stream>>>(xpad, W4a, out);
  inorm_stats_k<<<128, 256, 0, stream>>>(out, stats);
  apply_pack_k<<<2048, 256, 0, stream>>>(x, out, stats, buf1, xpad);
  // conv-res block 2 (fused apply + LayerNorm; x2 never materialized)
  conv_mfma_k<<<512, 256, 0, stream>>>(xpad, W4b, out);
  inorm_stats_k<<<128, 256, 0, stream>>>(out, stats);
  apply_ln_k<<<2048, 256, 0, stream>>>(buf1, out, stats, ln_w, ln_b, lnx);

  // mamba: axis-independent projection once
  gemm_lr_k<<<1024, 256, 0, stream>>>(lnx, Wlr, Lbuf, Gbuf);

  // per-axis: dbc_k (conv1d+gemm fused) -> scan_k (seq-per-wave) -> gemm_out_k
  const int sh[3] = {10, 5, 0};
  for (int axis = 0; axis < 3; axis++){
    dbc_k<<<1024, 256, 0, stream>>>(Lbuf, c1dw, c1db, Wdbc, db, xl, dbc, sh[axis]);
    scan_k<<<512, 256, 0, stream>>>(dbc, xl, Gbuf, negA2, pnw, pnb, Ybuf, axis);
    gemm_out_k<<<1024, 256, 0, stream>>>(Ybuf, oWp, axw, x, rsc, out, axis,
                                         axis == 0 ? 0 : (axis == 2 ? 2 : 1));
  }
}

// Round 11
// 604.715 us; speedup vs baseline: 1.1098x; 1.1098x over previous
//
#include <hip/hip_runtime.h>
#include <hip/hip_bf16.h>
#include <math.h>
#include <stdint.h>

// ---------------------------------------------------------------------------
// Full U-Mamba block. R11: out-projection hoisted across axes (linear: sum of
// wax*Y first, ONE gemm_out at end). scan_k accumulates wax-weighted Y into
// Yacc (bf16 RMW), with depth-1 load prefetch + float4 B/C LDS staging.
// Everything else = R9/R10 best (m97 conv, fused dbc, glue fusions).
// ---------------------------------------------------------------------------

typedef __attribute__((ext_vector_type(8))) short short8;   // 8 bf16 = 4 VGPR
typedef __attribute__((ext_vector_type(4))) float f32x4;

__device__ __forceinline__ float siluf(float x){ return x * (1.0f / (1.0f + __expf(-x))); }
__device__ __forceinline__ float softplusf(float x){ return fmaxf(x, 0.0f) + log1pf(__expf(-fabsf(x))); }
__device__ __forceinline__ float b2f(short s){
  unsigned int u = ((unsigned int)(unsigned short)s) << 16;
  float f; __builtin_memcpy(&f, &u, 4); return f;
}
__device__ __forceinline__ short f2b(float v){
  __hip_bfloat16 h = __float2bfloat16(v);
  unsigned short u; __builtin_memcpy(&u, &h, 2); return (short)u;
}

// async global->LDS, 16B per lane; LDS dest is wave-uniform base + lane*16.
__device__ __forceinline__ void gld_lds16(const void* g, void* l){
  __builtin_amdgcn_global_load_lds(
      (__attribute__((address_space(1))) void*)(uintptr_t)g,
      (__attribute__((address_space(3))) void*)(uint32_t)(uintptr_t)l,
      16, 0, 0);
}

// ---------------------------------------------------------------------------
// One-shot setup: zero xpad | pack conv weights a/b -> bf16 [tap][co][ci] |
// mamba weight bf16 tables | negA2[s] = -softplus(A_log[s]) * log2(e).
// ---------------------------------------------------------------------------
__global__ __launch_bounds__(256) void setup_k(uint4* __restrict__ xz,
    const float* __restrict__ cr1w, const float* __restrict__ cr2w,
    const float* __restrict__ lw, const float* __restrict__ rwt,
    const float* __restrict__ dwt, const float* __restrict__ bw,
    const float* __restrict__ cwp, const float* __restrict__ owt,
    const float* __restrict__ alog,
    __hip_bfloat16* __restrict__ W4a, __hip_bfloat16* __restrict__ W4b,
    __hip_bfloat16* __restrict__ Wlr, __hip_bfloat16* __restrict__ Wd,
    __hip_bfloat16* __restrict__ oWp, float* __restrict__ negA2)
{
  int i = blockIdx.x * 256 + threadIdx.x;
  if (i < 628864){ uint4 z; z.x = z.y = z.z = z.w = 0u; xz[i] = z; return; }
  i -= 628864;
  if (i < 110592){
    int tap = i >> 12, co = (i >> 6) & 63, ci = i & 63;
    W4a[i] = __float2bfloat16(cr1w[(co * 64 + ci) * 27 + tap]); return;
  }
  i -= 110592;
  if (i < 110592){
    int tap = i >> 12, co = (i >> 6) & 63, ci = i & 63;
    W4b[i] = __float2bfloat16(cr2w[(co * 64 + ci) * 27 + tap]); return;
  }
  i -= 110592;
  if (i < 16384){
    int row = i >> 6, c = i & 63;
    float v = (row < 128) ? lw[row * 64 + c] : rwt[(row - 128) * 64 + c];
    Wlr[i] = __float2bfloat16(v); return;
  }
  i -= 16384;
  if (i < 20480){
    int row = i >> 7, k = i & 127;
    float v = (row < 128) ? dwt[row * 128 + k]
            : (row < 144 ? bw[(row - 128) * 128 + k] : cwp[(row - 144) * 128 + k]);
    Wd[i] = __float2bfloat16(v); return;
  }
  i -= 20480;
  if (i < 8192){ oWp[i] = __float2bfloat16(owt[i]); return; }
  i -= 8192;
  if (i < 16){ negA2[i] = -softplusf(alog[i]) * 1.44269504088896f; return; }
}

// ---------------------------------------------------------------------------
// Pack fp32 NCDHW -> padded channels-last bf16 [b][h+1][w+1][d+1][c] (conv1).
// ---------------------------------------------------------------------------
__global__ __launch_bounds__(256) void pack_k(const float* __restrict__ xin,
                                              __hip_bfloat16* __restrict__ xpad)
{
  __shared__ float lds[64 * 33];
  const int t = threadIdx.x, blk = blockIdx.x;
  const int b = blk >> 10, h = (blk >> 5) & 31, w = blk & 31;
  const size_t rbase = ((size_t)(b * 64) << 15) + h * 1024 + w * 32;
  #pragma unroll
  for (int r = 0; r < 8; r++){
    int c = r * 8 + (t >> 5), d = t & 31;
    lds[c * 33 + d] = xin[rbase + (size_t)c * 32768 + d];
  }
  __syncthreads();
  const size_t wbase = (size_t)b * 2515456 + (size_t)(h + 1) * 73984 + (w + 1) * 2176 + 64;
  #pragma unroll
  for (int r = 0; r < 8; r++){
    int d = r * 4 + (t >> 6), c = t & 63;
    xpad[wbase + d * 64 + c] = __float2bfloat16(lds[c * 33 + d]);
  }
}

// ---------------------------------------------------------------------------
// Conv3d implicit GEMM, bf16 MFMA 16x16x32, LDS-staged (m97 pattern, R8).
// ---------------------------------------------------------------------------
__global__ __launch_bounds__(256) void conv_mfma_k(const __hip_bfloat16* __restrict__ xpad,
    const __hip_bfloat16* __restrict__ W4, float* __restrict__ y)
{
  __shared__ short smem[6144];   // [0,4096): B tile; [4096,6144): A tile

  const int t = threadIdx.x;
  const int wave = t >> 6, lane = t & 63;
  const int quad = lane >> 4, ln = lane & 15;

  const int blk = blockIdx.x;          // 512 blocks
  const int xcd = blk & 7, j = blk >> 3;
  const int b = j >> 5, jj = j & 31;
  const int h = xcd * 4 + (jj >> 3);
  const int w0 = (jj & 7) * 4;

  const int bcol = (lane >> 2) * 64 + (lane & 3) * 8;
  const __hip_bfloat16* Bg = xpad + (size_t)b * 2515456 + (size_t)h * 73984
                                  + (size_t)(w0 + wave) * 2176 + bcol;
  const __hip_bfloat16* Ag = W4 + wave * 1024 + bcol;
  short* Bl0 = &smem[wave * 1024];
  short* Bl1 = &smem[wave * 1024 + 512];
  short* Al  = &smem[4096 + wave * 512];

  f32x4 acc[2][4];
  #pragma unroll
  for (int jn = 0; jn < 2; jn++)
    #pragma unroll
    for (int m = 0; m < 4; m++) acc[jn][m] = (f32x4){0.f, 0.f, 0.f, 0.f};

  const int aoff = ln * 32 + quad * 8;
  const int boff = (wave * 32 + ln) * 32 + quad * 8;

  for (int s = 0; s < 54; s++){
    const int t1 = s >> 1, ch = s & 1;
    const int ki = t1 / 9, kj = (t1 / 3) % 3, kk = t1 % 3;
    const int tapoff = ki * 73984 + kj * 2176 + kk * 64 + ch * 32;

    __syncthreads();
    gld_lds16(Bg + tapoff,        Bl0);
    gld_lds16(Bg + tapoff + 1024, Bl1);
    gld_lds16(Ag + t1 * 4096 + ch * 32, Al);
    __syncthreads();

    short8 a0 = *(const short8*)&smem[4096 + aoff];
    short8 a1 = *(const short8*)&smem[4096 + 512 + aoff];
    short8 a2 = *(const short8*)&smem[4096 + 1024 + aoff];
    short8 a3 = *(const short8*)&smem[4096 + 1536 + aoff];
    short8 b0 = *(const short8*)&smem[boff];
    short8 b1 = *(const short8*)&smem[boff + 512];

    acc[0][0] = __builtin_amdgcn_mfma_f32_16x16x32_bf16(a0, b0, acc[0][0], 0, 0, 0);
    acc[0][1] = __builtin_amdgcn_mfma_f32_16x16x32_bf16(a1, b0, acc[0][1], 0, 0, 0);
    acc[0][2] = __builtin_amdgcn_mfma_f32_16x16x32_bf16(a2, b0, acc[0][2], 0, 0, 0);
    acc[0][3] = __builtin_amdgcn_mfma_f32_16x16x32_bf16(a3, b0, acc[0][3], 0, 0, 0);
    acc[1][0] = __builtin_amdgcn_mfma_f32_16x16x32_bf16(a0, b1, acc[1][0], 0, 0, 0);
    acc[1][1] = __builtin_amdgcn_mfma_f32_16x16x32_bf16(a1, b1, acc[1][1], 0, 0, 0);
    acc[1][2] = __builtin_amdgcn_mfma_f32_16x16x32_bf16(a2, b1, acc[1][2], 0, 0, 0);
    acc[1][3] = __builtin_amdgcn_mfma_f32_16x16x32_bf16(a3, b1, acc[1][3], 0, 0, 0);
  }

  const size_t sbase = (size_t)h * 1024 + (w0 + wave) * 32 + ln;
  #pragma unroll
  for (int jn = 0; jn < 2; jn++){
    #pragma unroll
    for (int mt = 0; mt < 4; mt++){
      #pragma unroll
      for (int reg = 0; reg < 4; reg++){
        int co = mt * 16 + quad * 4 + reg;
        y[(((size_t)(b * 64 + co)) << 15) + sbase + jn * 16] = acc[jn][mt][reg];
      }
    }
  }
}

// ---------------------------------------------------------------------------
// InstanceNorm3d stats: one block per (b,c); stats[g]=mu, stats[128+g]=rsigma.
// ---------------------------------------------------------------------------
__global__ __launch_bounds__(256) void inorm_stats_k(const float* __restrict__ y,
                                                     float* __restrict__ stats)
{
  __shared__ float ss[256], ss2[256];
  const int t = threadIdx.x, g = blockIdx.x;
  const float* p = y + (size_t)g * 32768;
  float s = 0.0f, s2 = 0.0f;
  for (int i = t; i < 32768; i += 256){ float v = p[i]; s += v; s2 += v * v; }
  ss[t] = s; ss2[t] = s2;
  __syncthreads();
  for (int off = 128; off > 0; off >>= 1){
    if (t < off){ ss[t] += ss[t + off]; ss2[t] += ss2[t + off]; }
    __syncthreads();
  }
  if (t == 0){
    float mu = ss[0] * (1.0f / 32768.0f);
    float var = ss2[0] * (1.0f / 32768.0f) - mu * mu;
    stats[g] = mu;
    stats[128 + g] = rsqrtf(var + 1e-5f);
  }
}

// ---------------------------------------------------------------------------
// Fused: InstanceNorm-apply + LeakyReLU + residual -> x1 (fp32 NCDHW)
// AND bf16 channels-last re-pack into xpad (input of conv2).
// ---------------------------------------------------------------------------
__global__ __launch_bounds__(256) void apply_pack_k(const float* __restrict__ xin,
    const float* __restrict__ y, const float* __restrict__ stats,
    float* __restrict__ x1, __hip_bfloat16* __restrict__ xpad)
{
  __shared__ float lds[64 * 33];
  const int t = threadIdx.x, blk = blockIdx.x;
  const int b = blk >> 10, h = (blk >> 5) & 31, w = blk & 31;
  const size_t rbase = ((size_t)(b * 64) << 15) + h * 1024 + w * 32;
  #pragma unroll
  for (int r = 0; r < 8; r++){
    int c = r * 8 + (t >> 5), d = t & 31;
    float mu = stats[b * 64 + c], rs = stats[128 + b * 64 + c];
    float v = (y[rbase + (size_t)c * 32768 + d] - mu) * rs;
    v = (v >= 0.0f) ? v : 0.01f * v;
    v += xin[rbase + (size_t)c * 32768 + d];
    x1[rbase + (size_t)c * 32768 + d] = v;
    lds[c * 33 + d] = v;
  }
  __syncthreads();
  const size_t wbase = (size_t)b * 2515456 + (size_t)(h + 1) * 73984 + (w + 1) * 2176 + 64;
  #pragma unroll
  for (int r = 0; r < 8; r++){
    int d = r * 4 + (t >> 6), c = t & 63;
    xpad[wbase + d * 64 + c] = __float2bfloat16(lds[c * 33 + d]);
  }
}

// ---------------------------------------------------------------------------
// Fused: InstanceNorm-apply + LeakyReLU + residual + LayerNorm over C
// -> bf16 channels-last lnx [pos][64]. x2 never materialized.
// ---------------------------------------------------------------------------
__global__ __launch_bounds__(256) void apply_ln_k(const float* __restrict__ x1,
    const float* __restrict__ y, const float* __restrict__ stats,
    const float* __restrict__ lnw, const float* __restrict__ lnb,
    __hip_bfloat16* __restrict__ lnx)
{
  __shared__ float lds[64 * 33];
  __shared__ float s_mu[32], s_rs[32];
  const int t = threadIdx.x, blk = blockIdx.x;
  const int b = blk >> 10, h = (blk >> 5) & 31, w = blk & 31;
  const size_t rbase = ((size_t)(b * 64) << 15) + h * 1024 + w * 32;
  #pragma unroll
  for (int r = 0; r < 8; r++){
    int c = r * 8 + (t >> 5), d = t & 31;
    float mu = stats[b * 64 + c], rs = stats[128 + b * 64 + c];
    float v = (y[rbase + (size_t)c * 32768 + d] - mu) * rs;
    v = (v >= 0.0f) ? v : 0.01f * v;
    lds[c * 33 + d] = v + x1[rbase + (size_t)c * 32768 + d];
  }
  __syncthreads();
  if (t < 32){
    float s = 0.f, s2 = 0.f;
    for (int c = 0; c < 64; c++){ float v = lds[c * 33 + t]; s += v; s2 += v * v; }
    float mu = s * (1.f / 64.f);
    float var = s2 * (1.f / 64.f) - mu * mu;
    s_mu[t] = mu; s_rs[t] = rsqrtf(var + 1e-5f);
  }
  __syncthreads();
  const int d = t >> 3, c0 = (t & 7) * 8;
  const int pos = b * 32768 + h * 1024 + w * 32 + d;
  const float mu = s_mu[d], rs = s_rs[d];
  short8 o;
  #pragma unroll
  for (int j = 0; j < 8; j++){
    int c = c0 + j;
    o[j] = f2b((lds[c * 33 + d] - mu) * rs * lnw[c] + lnb[c]);
  }
  *(short8*)&lnx[(size_t)pos * 64 + c0] = o;
}

// ---------------------------------------------------------------------------
// GEMM [65536,64] x [64,256] -> Lbuf (cols 0-127 raw) + Gbuf (silu, 128-255).
// ---------------------------------------------------------------------------
__global__ __launch_bounds__(256) void gemm_lr_k(const __hip_bfloat16* __restrict__ lnx,
    const __hip_bfloat16* __restrict__ Wlr, __hip_bfloat16* __restrict__ Lb,
    __hip_bfloat16* __restrict__ Gb)
{
  const int t = threadIdx.x, wave = t >> 6, lane = t & 63, quad = lane >> 4, ln = lane & 15;
  const int pos0 = blockIdx.x * 64 + wave * 16;
  f32x4 acc[16];
  #pragma unroll
  for (int nt = 0; nt < 16; nt++) acc[nt] = (f32x4){0.f, 0.f, 0.f, 0.f};
  #pragma unroll
  for (int ks = 0; ks < 2; ks++){
    short8 a = *(const short8*)&lnx[(size_t)(pos0 + ln) * 64 + ks * 32 + quad * 8];
    #pragma unroll
    for (int nt = 0; nt < 16; nt++){
      short8 bv = *(const short8*)&Wlr[(nt * 16 + ln) * 64 + ks * 32 + quad * 8];
      acc[nt] = __builtin_amdgcn_mfma_f32_16x16x32_bf16(a, bv, acc[nt], 0, 0, 0);
    }
  }
  #pragma unroll
  for (int nt = 0; nt < 16; nt++){
    int col = nt * 16 + ln;
    #pragma unroll
    for (int reg = 0; reg < 4; reg++){
      int pos = pos0 + quad * 4 + reg;
      float v = acc[nt][reg];
      if (col < 128) Lb[(size_t)pos * 128 + col] = __float2bfloat16(v);
      else           Gb[(size_t)pos * 128 + col - 128] = __float2bfloat16(siluf(v));
    }
  }
}

// ---------------------------------------------------------------------------
// FUSED per-axis: conv1d(k=4)+silu -> LDS tile -> GEMM [64,128]x[128,160].
// ---------------------------------------------------------------------------
__global__ __launch_bounds__(256) void dbc_k(const __hip_bfloat16* __restrict__ Lb,
    const float* __restrict__ cw, const float* __restrict__ cb,
    const __hip_bfloat16* __restrict__ Wd, const float* __restrict__ db,
    __hip_bfloat16* __restrict__ xl, __hip_bfloat16* __restrict__ dbc, int sh)
{
  __shared__ short s_xl[64 * 136];
  const int t = threadIdx.x;
  const int pos0 = blockIdx.x * 64;
  const int sigma = 1 << sh;

  const int c0 = (t & 15) * 8;
  const int pibase = t >> 4;
  float4 w4[8]; float cbv[8];
  #pragma unroll
  for (int c = 0; c < 8; c++){ w4[c] = *(const float4*)&cw[(c0 + c) * 4]; cbv[c] = cb[c0 + c]; }

  #pragma unroll
  for (int r = 0; r < 4; r++){
    int pi = pibase + r * 16;
    int pos = pos0 + pi;
    int l = (pos >> sh) & 31;
    float acc[8];
    #pragma unroll
    for (int c = 0; c < 8; c++) acc[c] = cbv[c];
    #pragma unroll
    for (int j = 0; j < 4; j++){
      int off = 3 - j;
      if (l >= off){
        short8 lv = *(const short8*)&Lb[(size_t)(pos - off * sigma) * 128 + c0];
        #pragma unroll
        for (int c = 0; c < 8; c++){
          float wv = (j == 0) ? w4[c].x : (j == 1) ? w4[c].y : (j == 2) ? w4[c].z : w4[c].w;
          acc[c] += wv * b2f(lv[c]);
        }
      }
    }
    short8 o;
    #pragma unroll
    for (int c = 0; c < 8; c++) o[c] = f2b(siluf(acc[c]));
    *(short8*)&s_xl[pi * 136 + c0] = o;
    *(short8*)&xl[(size_t)pos * 128 + c0] = o;
  }
  __syncthreads();

  const int wave = t >> 6, lane = t & 63, quad = lane >> 4, ln = lane & 15;
  const int rowb = (wave * 16 + ln) * 136;
  f32x4 acc2[10];
  #pragma unroll
  for (int nt = 0; nt < 10; nt++) acc2[nt] = (f32x4){0.f, 0.f, 0.f, 0.f};
  #pragma unroll
  for (int ks = 0; ks < 4; ks++){
    short8 a = *(const short8*)&s_xl[rowb + ks * 32 + quad * 8];
    #pragma unroll
    for (int nt = 0; nt < 10; nt++){
      short8 bv = *(const short8*)&Wd[(nt * 16 + ln) * 128 + ks * 32 + quad * 8];
      acc2[nt] = __builtin_amdgcn_mfma_f32_16x16x32_bf16(a, bv, acc2[nt], 0, 0, 0);
    }
  }
  const int posw = pos0 + wave * 16 + quad * 4;
  #pragma unroll
  for (int nt = 0; nt < 10; nt++){
    int col = nt * 16 + ln;
    bool isd = col < 128;
    float dbv = isd ? db[col] : 0.f;
    #pragma unroll
    for (int reg = 0; reg < 4; reg++){
      float v = acc2[nt][reg];
      if (isd) v = fminf(fmaxf(softplusf(v + dbv), 1e-4f), 10.f);
      dbc[(size_t)(posw + reg) * 160 + col] = __float2bfloat16(v);
    }
  }
}

// ---------------------------------------------------------------------------
// Per-axis selective scan + gate + post-LN + wax-weighted ACCUMULATE into
// Yacc (bf16, pos-major). One sequence per wave; lane owns 2 channels.
// R11: depth-1 prefetch of per-l loads; float4 LDS staging for B/C.
// first=1: store wax*y; else: Yacc += wax*y.
// ---------------------------------------------------------------------------
__global__ __launch_bounds__(256) void scan_k(const __hip_bfloat16* __restrict__ dbc,
    const __hip_bfloat16* __restrict__ xl, const __hip_bfloat16* __restrict__ Gb,
    const float* __restrict__ negA2, const float* __restrict__ pnw,
    const float* __restrict__ pnb, const float* __restrict__ axw,
    __hip_bfloat16* __restrict__ Yacc, int axis, int first)
{
  __shared__ float s_BC[4][1024];   // per wave: [0..511]=B, [512..1023]=C
  const int t = threadIdx.x;
  const int wv = t >> 6, lane = t & 63;
  const int seq = blockIdx.x * 4 + wv;
  const int b = seq >> 10, r1 = (seq >> 5) & 31, r0 = seq & 31;
  int base, sigma;
  if (axis == 0){      base = b * 32768 + r1 * 32 + r0;        sigma = 1024; }
  else if (axis == 1){ base = b * 32768 + r1 * 1024 + r0;      sigma = 32; }
  else {               base = b * 32768 + r1 * 1024 + r0 * 32; sigma = 1; }

  float* sB = s_BC[wv];
  float* sC = s_BC[wv] + 512;
  #pragma unroll
  for (int i = 0; i < 2; i++){
    int c = lane * 2 + i;
    int row = c >> 2, sub = c & 3;
    short8 v = *(const short8*)&dbc[(size_t)(base + row * sigma) * 160 + 128 + sub * 8];
    float* dst = (sub < 2) ? &sB[row * 16 + sub * 8] : &sC[row * 16 + (sub - 2) * 8];
    float4 f0 = {b2f(v[0]), b2f(v[1]), b2f(v[2]), b2f(v[3])};
    float4 f1 = {b2f(v[4]), b2f(v[5]), b2f(v[6]), b2f(v[7])};
    *(float4*)dst = f0;
    *(float4*)(dst + 4) = f1;
  }
  float A2[16], h0[16], h1[16];
  #pragma unroll
  for (int s = 0; s < 16; s++){ A2[s] = negA2[s]; h0[s] = 0.f; h1[s] = 0.f; }

  float a0 = axw[0], a1 = axw[1], a2 = axw[2];
  float mxw = fmaxf(a0, fmaxf(a1, a2));
  float e0 = __expf(a0 - mxw), e1 = __expf(a1 - mxw), e2 = __expf(a2 - mxw);
  float wax = ((axis == 0) ? e0 : (axis == 1) ? e1 : e2) / (e0 + e1 + e2);
  __syncthreads();

  const int d0 = lane * 2;
  const float pw0 = pnw[d0], pb0 = pnb[d0];
  const float pw1 = pnw[d0 + 1], pb1 = pnb[d0 + 1];
  const __hip_bfloat16* pd = dbc  + (size_t)base * 160 + d0;
  const __hip_bfloat16* px = xl   + (size_t)base * 128 + d0;
  const __hip_bfloat16* pg = Gb   + (size_t)base * 128 + d0;
  __hip_bfloat16*       py = Yacc + (size_t)base * 128 + d0;
  const size_t sd = (size_t)sigma * 160;
  const size_t sx = (size_t)sigma * 128;

  unsigned int du, xu, gu, yu = 0;
  __builtin_memcpy(&du, pd, 4);
  __builtin_memcpy(&xu, px, 4);
  __builtin_memcpy(&gu, pg, 4);
  if (!first) __builtin_memcpy(&yu, py, 4);

  for (int l = 0; l < 32; l++){
    unsigned int ndu = 0, nxu = 0, ngu = 0, nyu = 0;
    if (l + 1 < 32){
      __builtin_memcpy(&ndu, pd + sd, 4);
      __builtin_memcpy(&nxu, px + sx, 4);
      __builtin_memcpy(&ngu, pg + sx, 4);
      if (!first) __builtin_memcpy(&nyu, py + sx, 4);
    }
    float dt0 = b2f((short)(du & 0xffff)), dt1 = b2f((short)(du >> 16));
    float xt0 = b2f((short)(xu & 0xffff)), xt1 = b2f((short)(xu >> 16));
    float g0  = b2f((short)(gu & 0xffff)), g1  = b2f((short)(gu >> 16));
    float dx0 = dt0 * xt0, dx1 = dt1 * xt1;
    float y0 = 0.f, y1 = 0.f;
    const float* Bl = &sB[l * 16];
    const float* Cl = &sC[l * 16];
    #pragma unroll
    for (int s = 0; s < 16; s++){
      float Bv = Bl[s], Cv = Cl[s];
      h0[s] = exp2f(dt0 * A2[s]) * h0[s] + dx0 * Bv;
      h1[s] = exp2f(dt1 * A2[s]) * h1[s] + dx1 * Bv;
      y0 += h0[s] * Cv;
      y1 += h1[s] * Cv;
    }
    y0 *= g0; y1 *= g1;
    // post-LN over d_inner=128 (64 lanes x 2): in-wave butterfly
    float s1 = y0 + y1, s2 = y0 * y0 + y1 * y1;
    #pragma unroll
    for (int m = 1; m < 64; m <<= 1){
      s1 += __shfl_xor(s1, m);
      s2 += __shfl_xor(s2, m);
    }
    float mu = s1 * (1.f / 128.f);
    float var = s2 * (1.f / 128.f) - mu * mu;
    float rs = rsqrtf(fmaxf(var, 0.f) + 1e-5f);
    float o0 = ((y0 - mu) * rs * pw0 + pb0) * wax;
    float o1 = ((y1 - mu) * rs * pw1 + pb1) * wax;
    if (!first){
      o0 += b2f((short)(yu & 0xffff));
      o1 += b2f((short)(yu >> 16));
    }
    unsigned short q0 = (unsigned short)f2b(o0);
    unsigned short q1 = (unsigned short)f2b(o1);
    unsigned int ov = (unsigned int)q0 | ((unsigned int)q1 << 16);
    __builtin_memcpy(py, &ov, 4);
    du = ndu; xu = nxu; gu = ngu; yu = nyu;
    pd += sd; px += sx; pg += sx; py += sx;
  }
}

// ---------------------------------------------------------------------------
// SINGLE out-projection GEMM (Yacc already holds sum of wax-weighted Y over
// all 3 axes) + residual finalize: out = x + rs * (Yacc @ oW^T). Coalesced.
// ---------------------------------------------------------------------------
__global__ __launch_bounds__(256) void gemm_out_k(const __hip_bfloat16* __restrict__ Yb,
    const __hip_bfloat16* __restrict__ oW, const float* __restrict__ xres,
    const float* __restrict__ rsc, float* __restrict__ outp)
{
  const int t = threadIdx.x, wave = t >> 6, lane = t & 63, quad = lane >> 4, ln = lane & 15;
  const int pos0 = blockIdx.x * 64 + wave * 16;
  f32x4 acc[4];
  #pragma unroll
  for (int mt = 0; mt < 4; mt++) acc[mt] = (f32x4){0.f, 0.f, 0.f, 0.f};
  #pragma unroll
  for (int ks = 0; ks < 4; ks++){
    short8 bv = *(const short8*)&Yb[(size_t)(pos0 + ln) * 128 + ks * 32 + quad * 8];
    #pragma unroll
    for (int mt = 0; mt < 4; mt++){
      short8 a = *(const short8*)&oW[(mt * 16 + ln) * 128 + ks * 32 + quad * 8];
      acc[mt] = __builtin_amdgcn_mfma_f32_16x16x32_bf16(a, bv, acc[mt], 0, 0, 0);
    }
  }
  float rs = rsc[0];
  const int pos = pos0 + ln;
  const int bb = pos >> 15, hwd = pos & 32767;
  #pragma unroll
  for (int mt = 0; mt < 4; mt++){
    #pragma unroll
    for (int reg = 0; reg < 4; reg++){
      int co = mt * 16 + quad * 4 + reg;
      size_t idx = (((size_t)(bb * 64 + co)) << 15) + hwd;
      outp[idx] = xres[idx] + rs * acc[mt][reg];
    }
  }
}

// ---------------------------------------------------------------------------
extern "C" void kernel_launch(void* const* d_in, const int* in_sizes, int n_in,
                              void* d_out, int out_size, void* d_ws, size_t ws_size,
                              hipStream_t stream)
{
  const float* x      = (const float*)d_in[0];
  const float* cr1w   = (const float*)d_in[1];
  const float* cr2w   = (const float*)d_in[3];
  const float* ln_w   = (const float*)d_in[5];
  const float* ln_b   = (const float*)d_in[6];
  const float* left_w = (const float*)d_in[7];
  const float* c1dw   = (const float*)d_in[8];
  const float* c1db   = (const float*)d_in[9];
  const float* dw     = (const float*)d_in[10];
  const float* db     = (const float*)d_in[11];
  const float* bpw    = (const float*)d_in[12];
  const float* cpw    = (const float*)d_in[13];
  const float* alog   = (const float*)d_in[14];
  const float* rw     = (const float*)d_in[15];
  const float* pnw    = (const float*)d_in[16];
  const float* pnb    = (const float*)d_in[17];
  const float* ow     = (const float*)d_in[18];
  const float* rsc    = (const float*)d_in[19];
  const float* axw    = (const float*)d_in[20];
  float* out = (float*)d_out;                       // conv raw out, then final out
  float* wsf = (float*)d_ws;

  float* buf1   = wsf;                                         // x1 fp32; later xl bf16 alias
  float* stats  = wsf + 4194304;                               // 256 f
  float* negA2  = wsf + 4194560;                               // 16 f
  __hip_bfloat16* W4a  = (__hip_bfloat16*)(wsf + 4194816);     // 110,592 bf16
  __hip_bfloat16* W4b  = W4a + 110592;
  __hip_bfloat16* Wlr  = (__hip_bfloat16*)(wsf + 4305408);     // 16,384 bf16
  __hip_bfloat16* Wdbc = (__hip_bfloat16*)(wsf + 4313600);     // 20,480 bf16
  __hip_bfloat16* oWp  = (__hip_bfloat16*)(wsf + 4323840);     // 8,192 bf16
  __hip_bfloat16* xpad = (__hip_bfloat16*)(wsf + 4327936);     // 5,030,912 bf16
  __hip_bfloat16* lnx  = xpad;                                 // alias (post-conv)
  __hip_bfloat16* Lbuf = (__hip_bfloat16*)(wsf + 6843392);     // 8,388,608 bf16
  __hip_bfloat16* Gbuf = (__hip_bfloat16*)(wsf + 11037696);    // 8,388,608 bf16
  __hip_bfloat16* dbc  = (__hip_bfloat16*)(wsf + 15232000);    // 10,485,760 bf16
  __hip_bfloat16* Yacc = (__hip_bfloat16*)(wsf + 20474880);    // 8,388,608 bf16
  __hip_bfloat16* xl   = (__hip_bfloat16*)buf1;                // alias (x1 dead after apply_ln)

  setup_k<<<3497, 256, 0, stream>>>((uint4*)xpad, cr1w, cr2w, left_w, rw, dw, bpw, cpw, ow,
                                    alog, W4a, W4b, Wlr, Wdbc, oWp, negA2);

  // conv-res block 1
  pack_k<<<2048, 256, 0, stream>>>(x, xpad);
  conv_mfma_k<<<512, 256, 0, stream>>>(xpad, W4a, out);
  inorm_stats_k<<<128, 256, 0, stream>>>(out, stats);
  apply_pack_k<<<2048, 256, 0, stream>>>(x, out, stats, buf1, xpad);
  // conv-res block 2 (fused apply + LayerNorm; x2 never materialized)
  conv_mfma_k<<<512, 256, 0, stream>>>(xpad, W4b, out);
  inorm_stats_k<<<128, 256, 0, stream>>>(out, stats);
  apply_ln_k<<<2048, 256, 0, stream>>>(buf1, out, stats, ln_w, ln_b, lnx);

  // mamba: axis-independent projection once
  gemm_lr_k<<<1024, 256, 0, stream>>>(lnx, Wlr, Lbuf, Gbuf);

  // per-axis: dbc_k -> scan_k (accumulates wax-weighted Y into Yacc)
  const int sh[3] = {10, 5, 0};
  for (int axis = 0; axis < 3; axis++){
    dbc_k<<<1024, 256, 0, stream>>>(Lbuf, c1dw, c1db, Wdbc, db, xl, dbc, sh[axis]);
    scan_k<<<512, 256, 0, stream>>>(dbc, xl, Gbuf, negA2, pnw, pnb, axw, Yacc,
                                    axis, axis == 0 ? 1 : 0);
  }
  // single out-projection + residual finalize
  gemm_out_k<<<1024, 256, 0, stream>>>(Yacc, oWp, x, rsc, out);
}